// Round 1
// baseline (343.928 us; speedup 1.0000x reference)
//
#include <hip/hip_runtime.h>
#include <hip/hip_bf16.h>
#include <hip/hip_fp16.h>
#include <math.h>

#ifndef M_PI
#define M_PI 3.14159265358979323846
#endif

// Problem constants
#define NN 10000      // nodes
#define NE 160000     // edges
#define NC 16         // channels
#define NQ 5          // 2*order+1
#define NFR 10        // N_FREQ * N_RINGS
#define CQ 80         // NC*NQ (K per fr)
#define OP 80         // outputs per node
#define KTOT 800      // GEMM K
#define WSZ 64000     // 80*800 weight elements

#define MT 64         // edges per group in edge GEMM (v11: was 32)
#define GPB 2         // edge groups per block (amortizes B-register preload)
#define CSTRIDE 168   // chunk row stride in fp16 elems (160 + 8 pad; 336 B, 16B-aligned)

typedef __attribute__((ext_vector_type(8))) _Float16 f16x8;
typedef __attribute__((ext_vector_type(4))) float f32x4;

// RNE float->fp16 (values well within fp16 range: |A|<~500, |W|<~0.5)
static __device__ __forceinline__ unsigned short f2h_u(float f) {
    return __builtin_bit_cast(unsigned short, (_Float16)f);
}
static __device__ __forceinline__ unsigned pack2h(float lo, float hi) {
    return (unsigned)f2h_u(lo) | ((unsigned)f2h_u(hi) << 16);
}

// ---------------------------------------------------------------------------
// Reorder + convert W into MFMA-B FRAGMENT ORDER with NATURAL k (R5's k map):
//   Wt_frag[((ks*5+nt)*64 + lane)*8 + j] = fp16( W at n=16*nt+lrow,
//                                                k = 32*ks + 8*quad + j )
// Verified R10: value-identical GEMM, coalesced lane*16B B-loads.
// ---------------------------------------------------------------------------
__global__ void reorder_wt(const float* __restrict__ W1, const float* __restrict__ W2,
                           unsigned short* __restrict__ Wt1, unsigned short* __restrict__ Wt2) {
    int i = blockIdx.x * blockDim.x + threadIdx.x;  // over 64000
    if (i >= WSZ) return;
    int j    = i & 7;
    int lane = (i >> 3) & 63;
    int grp  = i >> 9;           // 0..124 = ks*5 + nt
    int ks   = grp / 5;
    int nt   = grp % 5;
    int quad = lane >> 4;
    int lrow = lane & 15;
    int n    = 16 * nt + lrow;
    int k    = 32 * ks + 8 * quad + j;   // natural k (R5)
    int fr = k / CQ, cq = k % CQ;
    int c = cq / NQ, q = cq % NQ;
    int f = fr / 2,  r = fr % 2;
    int o = n / NQ,  p = n % NQ;
    int src = ((((o * NC + c) * NQ + p) * NQ + q) * 5 + f) * 2 + r;
    Wt1[i] = f2h_u(W1[src]);
    Wt2[i] = f2h_u(W2[src]);
}

// ---------------------------------------------------------------------------
// Self-interaction + bias (fp32): y[n,op] = sum_cq x[n,cq]*Ws[o,c,p,q] + (p==0)b[o]
// Full write — serves as init before edge atomics.
// ---------------------------------------------------------------------------
__global__ void selfint(const float* __restrict__ xin, const float* __restrict__ Ws,
                        const float* __restrict__ b, float* __restrict__ y) {
    __shared__ float ws_s[NC * NC * NQ * NQ];  // 25.6 KB
    int tid = threadIdx.x;
    for (int i = tid; i < NC * NC * NQ * NQ; i += blockDim.x) ws_s[i] = Ws[i];
    __syncthreads();
    int idx = blockIdx.x * blockDim.x + tid;     // over N*80
    if (idx >= NN * OP) return;
    int n = idx / OP, op = idx % OP;
    int o = op / NQ, p = op % NQ;
    const float* xrow = xin + n * CQ;
    float acc = (p == 0) ? b[o] : 0.0f;
    #pragma unroll
    for (int c = 0; c < NC; ++c)
        #pragma unroll
        for (int q = 0; q < NQ; ++q)
            acc = fmaf(xrow[c * NQ + q], ws_s[o * 400 + c * 25 + p * 5 + q], acc);
    y[idx] = acc;
}

// ---------------------------------------------------------------------------
// Edge conv v11: W-STATIONARY restructure of the verified v10 kernel.
//
// v10 cost model: every wave re-read the full 128 KB Wt from global inside the
// MFMA loop (125 dwordx4 loads/thread) -> ~1.28 GB L2 B-traffic per layer and
// 125 VMEM latency chains threaded through the MFMA stream (MfmaUtil ~1 digit).
//
// v11: 5 waves/block; wave w owns output tile nt=w and preloads its B slice
// (all K=800 for 16 outputs) ONCE into 100 VGPRs (breg[25], compile-time
// indexed). MT=64 edges/group, GPB=2 groups/block -> 1250 blocks; B global
// traffic drops 8x (1.28 GB -> 160 MB/layer) and the inner loop has ZERO
// global loads. A staged in LDS chunks of K=160, DOUBLE-BUFFERED (2 x 21 KB),
// one barrier per chunk: staging VALU overlaps MFMA even at 1 block/CU.
//
// Numerics: identical fp16 A/B values, identical per-(edge,op) k-accumulation
// order (ch outer, s inner) as verified v10 -> bit-identical outputs.
// VGPR ~180 (breg 100 + xt 20 + tv 10 + acc 16 + temps) -> fits (320,2).
// ---------------------------------------------------------------------------
#define STAGE(CH, BUF)                                                          \
    if (tid < 256) {                                                            \
        _Pragma("unroll")                                                       \
        for (int frl = 0; frl < 2; ++frl) {                                     \
            const float tf = tv[2 * (CH) + frl];                                \
            uint2* dp = (uint2*)&A_s[BUF][el * CSTRIDE + frl * CQ + 20 * q4];   \
            _Pragma("unroll")                                                   \
            for (int j = 0; j < 5; ++j) {                                       \
                unsigned lo = pack2h(xt[4 * j + 0] * tf, xt[4 * j + 1] * tf);   \
                unsigned hi = pack2h(xt[4 * j + 2] * tf, xt[4 * j + 3] * tf);   \
                dp[j] = make_uint2(lo, hi);                                     \
            }                                                                   \
        }                                                                       \
    }

__global__ __launch_bounds__(320, 2)
void edge_conv_mfma(const float* __restrict__ xin, const int* __restrict__ ei,
                    const float* __restrict__ pre, const float* __restrict__ phi_arr,
                    const unsigned short* __restrict__ Wt, float* __restrict__ y) {
    __shared__ __align__(16) unsigned short A_s[2][MT * CSTRIDE];  // 2 x 21,504 B

    const int tid  = threadIdx.x;
    const int nt   = tid >> 6;          // wave index == output tile (5 waves)
    const int lane = tid & 63;
    const int lrow = lane & 15;
    const int quad = lane >> 4;

    // ---- B stationary: wave nt's slice of Wt, all K, in 100 VGPRs ----
    const f16x8* __restrict__ wf = (const f16x8*)Wt;
    f16x8 breg[25];
    #pragma unroll
    for (int ks = 0; ks < 25; ++ks)
        breg[ks] = wf[(ks * 5 + nt) * 64 + lane];

    // staging role (threads 0..255 = waves 0..3): 4 threads/edge, 64 edges
    const int el = tid >> 2;            // local edge 0..63 (valid when tid<256)
    const int q4 = tid & 3;             // cq quarter [20*q4, 20*q4+20)

    for (int g = 0; g < GPB; ++g) {
        const int e0 = (blockIdx.x * GPB + g) * MT;   // NE = 1250*2*64 exactly

        // ---- per-edge prep (identical math to v10) ----
        float xt[20];
        float tv[NFR];
        if (tid < 256) {
            const int e   = e0 + el;
            const int src = ei[2 * e];

            float s1, c1;
            sincosf(phi_arr[e], &s1, &c1);
            const float c2 = c1 * c1 - s1 * s1;
            const float s2 = 2.0f * c1 * s1;

            const float4* xp = (const float4*)(xin + (size_t)src * CQ + 20 * q4);
            #pragma unroll
            for (int k4 = 0; k4 < 5; ++k4) {
                float4 v = xp[k4];
                xt[4 * k4 + 0] = v.x; xt[4 * k4 + 1] = v.y;
                xt[4 * k4 + 2] = v.z; xt[4 * k4 + 3] = v.w;
            }
            #pragma unroll
            for (int cc = 0; cc < 4; ++cc) {    // rotate (1,2) by phi, (3,4) by 2phi
                float a1 = xt[cc * 5 + 1], b1 = xt[cc * 5 + 2];
                float a2 = xt[cc * 5 + 3], b2 = xt[cc * 5 + 4];
                xt[cc * 5 + 1] = c1 * a1 - s1 * b1;
                xt[cc * 5 + 2] = s1 * a1 + c1 * b1;
                xt[cc * 5 + 3] = c2 * a2 - s2 * b2;
                xt[cc * 5 + 4] = s2 * a2 + c2 * b2;
            }
            #pragma unroll
            for (int fr = 0; fr < NFR; ++fr) tv[fr] = pre[(size_t)(e0 + el) * NFR + fr];
        }

        // ---- K-chunk pipeline: stage(ch+1) overlaps MFMA(ch), 1 barrier/chunk
        STAGE(0, 0)
        __syncthreads();

        f32x4 acc[4];
        #pragma unroll
        for (int mt = 0; mt < 4; ++mt) acc[mt] = (f32x4){0.f, 0.f, 0.f, 0.f};

        #pragma unroll
        for (int ch = 0; ch < 5; ++ch) {
            if (ch < 4) { STAGE(ch + 1, (ch + 1) & 1) }

            const unsigned short* As_base = &A_s[ch & 1][0];
            #pragma unroll
            for (int s = 0; s < 5; ++s) {
                #pragma unroll
                for (int mt = 0; mt < 4; ++mt) {
                    f16x8 a = *(const f16x8*)(As_base + (16 * mt + lrow) * CSTRIDE + 32 * s + 8 * quad);
                    acc[mt] = __builtin_amdgcn_mfma_f32_16x16x32_f16(a, breg[5 * ch + s], acc[mt], 0, 0, 0);
                }
            }
            __syncthreads();   // chunk ch+1 staged AND chunk ch reads complete
        }

        // ---- scatter (reads ei directly; no LDS -> no extra barrier needed) ----
        #pragma unroll
        for (int mt = 0; mt < 4; ++mt) {
            #pragma unroll
            for (int r = 0; r < 4; ++r) {
                const int e = e0 + 16 * mt + quad * 4 + r;     // local edge row
                const int dst = ei[2 * e + 1];
                atomicAdd(y + (size_t)dst * OP + 16 * nt + lrow, acc[mt][r]);
            }
        }
    }
}

// ---------------------------------------------------------------------------
// Regular nonlinearity (+ optional residual). One thread per (n,c).
// ---------------------------------------------------------------------------
__global__ void nonlin(const float* __restrict__ yin, const float* __restrict__ res,
                       float* __restrict__ out) {
    int idx = blockIdx.x * blockDim.x + threadIdx.x;  // over N*C
    if (idx >= NN * NC) return;
    const float* vp = yin + (long long)idx * NQ;
    float a0 = vp[0], a1 = vp[1], a2 = vp[2], a3 = vp[3], a4 = vp[4];
    if (res != nullptr) {
        const float* rp = res + (long long)idx * NQ;
        a0 += rp[0]; a1 += rp[1]; a2 += rp[2]; a3 += rp[3]; a4 += rp[4];
    }
    float o0 = 0.f, o1 = 0.f, o2 = 0.f, o3 = 0.f, o4 = 0.f;
    #pragma unroll
    for (int k = 0; k < 7; ++k) {
        float th = (float)(2.0 * M_PI / 7.0) * (float)k;
        float c1k = cosf(th), s1k = sinf(th);
        float c2k = cosf(2.0f * th), s2k = sinf(2.0f * th);
        float s = a0 + a1 * c1k + a2 * s1k + a3 * c2k + a4 * s2k;
        s = fmaxf(s, 0.0f);
        o0 += s;
        o1 += s * c1k; o2 += s * s1k;
        o3 += s * c2k; o4 += s * s2k;
    }
    const float i7 = 1.0f / 7.0f, t7 = 2.0f / 7.0f;
    float* op = out + (long long)idx * NQ;
    op[0] = o0 * i7;
    op[1] = o1 * t7; op[2] = o2 * t7;
    op[3] = o3 * t7; op[4] = o4 * t7;
}

// ---------------------------------------------------------------------------
extern "C" void kernel_launch(void* const* d_in, const int* in_sizes, int n_in,
                              void* d_out, int out_size, void* d_ws, size_t ws_size,
                              hipStream_t stream) {
    const float* x    = (const float*)d_in[0];
    const int*   ei   = (const int*)d_in[1];      // int inputs arrive as int32
    const float* pre  = (const float*)d_in[2];
    const float* phi  = (const float*)d_in[3];
    const float* W1   = (const float*)d_in[4];
    const float* b1   = (const float*)d_in[5];
    const float* Ws1  = (const float*)d_in[6];
    const float* W2   = (const float*)d_in[7];
    const float* b2   = (const float*)d_in[8];
    const float* Ws2  = (const float*)d_in[9];
    float* out = (float*)d_out;

    // Workspace layout
    unsigned short* Wt1 = (unsigned short*)d_ws;          // 64000 fp16 = 128 KB
    unsigned short* Wt2 = Wt1 + WSZ;                      // 128 KB
    float* y1 = (float*)(Wt2 + WSZ);                      // 800000 f (3.2 MB)
    float* h  = y1 + (size_t)NN * OP;                     // 800000 f (3.2 MB)

    reorder_wt<<<(WSZ + 255) / 256, 256, 0, stream>>>(W1, W2, Wt1, Wt2);

    const int ecblocks = NE / (MT * GPB);   // 1250

    // Layer 1
    selfint<<<(NN * OP + 255) / 256, 256, 0, stream>>>(x, Ws1, b1, y1);
    edge_conv_mfma<<<ecblocks, 320, 0, stream>>>(x, ei, pre, phi, Wt1, y1);
    nonlin<<<(NN * NC + 255) / 256, 256, 0, stream>>>(y1, nullptr, h);

    // Layer 2 (reuse y1)
    selfint<<<(NN * OP + 255) / 256, 256, 0, stream>>>(h, Ws2, b2, y1);
    edge_conv_mfma<<<ecblocks, 320, 0, stream>>>(h, ei, pre, phi, Wt2, y1);

    // Residual + final nonlinearity -> d_out
    nonlin<<<(NN * NC + 255) / 256, 256, 0, stream>>>(y1, x, out);
}

// Round 2
// 315.557 us; speedup vs baseline: 1.0899x; 1.0899x over previous
//
#include <hip/hip_runtime.h>
#include <hip/hip_bf16.h>
#include <hip/hip_fp16.h>
#include <math.h>

#ifndef M_PI
#define M_PI 3.14159265358979323846
#endif

// Problem constants
#define NN 10000      // nodes
#define NE 160000     // edges
#define NC 16         // channels
#define NQ 5          // 2*order+1
#define NFR 10        // N_FREQ * N_RINGS
#define CQ 80         // NC*NQ
#define OP 80         // outputs per node
#define KTOT 800      // GEMM K
#define WSZ 64000     // 80*800 weight elements

#define APAD 808      // node-GEMM LDS row stride in fp16 (800+8: 1616 B, 20-dword
                      // stride -> 2-way-max bank aliasing on ds_read_b128 = free)

typedef __attribute__((ext_vector_type(8))) _Float16 f16x8;
typedef __attribute__((ext_vector_type(4))) float f32x4;

static __device__ __forceinline__ unsigned short f2h_u(float f) {
    return __builtin_bit_cast(unsigned short, (_Float16)f);
}

// ---------------------------------------------------------------------------
// Reorder + convert W into MFMA-B FRAGMENT ORDER with NATURAL k (verified R10):
//   Wt_frag[((ks*5+nt)*64 + lane)*8 + j] = fp16( W at n=16*nt+lrow,
//                                                k = 32*ks + 8*quad + j )
//   k decodes: fr = k/80, cq = k%80.
// ---------------------------------------------------------------------------
__global__ void reorder_wt(const float* __restrict__ W1, const float* __restrict__ W2,
                           unsigned short* __restrict__ Wt1, unsigned short* __restrict__ Wt2) {
    int i = blockIdx.x * blockDim.x + threadIdx.x;  // over 64000
    if (i >= WSZ) return;
    int j    = i & 7;
    int lane = (i >> 3) & 63;
    int grp  = i >> 9;           // 0..124 = ks*5 + nt
    int ks   = grp / 5;
    int nt   = grp % 5;
    int quad = lane >> 4;
    int lrow = lane & 15;
    int n    = 16 * nt + lrow;
    int k    = 32 * ks + 8 * quad + j;
    int fr = k / CQ, cq = k % CQ;
    int c = cq / NQ, q = cq % NQ;
    int f = fr / 2,  r = fr % 2;
    int o = n / NQ,  p = n % NQ;
    int src = ((((o * NC + c) * NQ + p) * NQ + q) * 5 + f) * 2 + r;
    Wt1[i] = f2h_u(W1[src]);
    Wt2[i] = f2h_u(W2[src]);
}

// ---------------------------------------------------------------------------
// CSR build (per launch; ei is the only dependency, reused by both layers).
// ---------------------------------------------------------------------------
__global__ void csr_hist(const int* __restrict__ ei, int* __restrict__ cnt) {
    int e = blockIdx.x * blockDim.x + threadIdx.x;
    if (e < NE) atomicAdd(&cnt[ei[2 * e + 1]], 1);
}

// single block, 256 threads: exclusive scan of cnt[NN] -> offs[NN+1], copy to cursor
__global__ void csr_scan(const int* __restrict__ cnt, int* __restrict__ offs,
                         int* __restrict__ cursor) {
    __shared__ int part[256];
    const int t = threadIdx.x;
    const int b0 = t * 40;                       // 250*40 = 10000
    const int myn = (b0 < NN) ? 40 : 0;
    int s = 0;
    for (int i = 0; i < myn; ++i) s += cnt[b0 + i];
    part[t] = s;
    __syncthreads();
    for (int d = 1; d < 256; d <<= 1) {          // Hillis-Steele inclusive scan
        int u = (t >= d) ? part[t - d] : 0;
        __syncthreads();
        part[t] += u;
        __syncthreads();
    }
    int run = (t == 0) ? 0 : part[t - 1];
    for (int i = 0; i < myn; ++i) {
        offs[b0 + i] = run;
        cursor[b0 + i] = run;
        run += cnt[b0 + i];
    }
    if (t == 255) offs[NN] = part[255];          // = NE
}

__global__ void csr_place(const int* __restrict__ ei, int* __restrict__ cursor,
                          int* __restrict__ eidcsr) {
    int e = blockIdx.x * blockDim.x + threadIdx.x;
    if (e < NE) {
        int pos = atomicAdd(&cursor[ei[2 * e + 1]], 1);
        eidcsr[pos] = e;
    }
}

// ---------------------------------------------------------------------------
// Aggregate v12: AggA[n, k] = sum_{e: dst=n} xt[e, k%80] * tv[e, k/80]  (fp32),
// written as fp16 in natural-k order [n][800]. One WAVE per node (CSR list),
// lane owns k = lane + 64*j (j<13). Per edge: lanes 0..15 stage the rotated
// source row into LDS (transport), lanes 16..25 stage tv; all 64 lanes then
// accumulate. Next-edge (e, src, phi) software prefetch hides the eidcsr->ei
// chain. Occupancy ~8 waves/SIMD (tiny LDS, ~70 VGPR) -> latency hidden by TLP.
// ---------------------------------------------------------------------------
__global__ __launch_bounds__(256)
void aggregate(const float* __restrict__ xin, const int* __restrict__ ei,
               const float* __restrict__ pre, const float* __restrict__ phi_arr,
               const int* __restrict__ offs, const int* __restrict__ eidcsr,
               unsigned short* __restrict__ Agg) {
    __shared__ float xts[4][CQ];
    __shared__ float tvs[4][NFR];
    const int tid = threadIdx.x;
    const int w = tid >> 6, lane = tid & 63;
    const int n = blockIdx.x * 4 + w;            // NN = 2500*4 exactly
    const int beg = offs[n], end = offs[n + 1];

    float acc[13];
    #pragma unroll
    for (int j = 0; j < 13; ++j) acc[j] = 0.f;

    int cqi[13], fri[13];                        // loop-invariant LDS indices
    #pragma unroll
    for (int j = 0; j < 13; ++j) {
        int k = lane + 64 * j;
        cqi[j] = k % CQ;
        fri[j] = k / CQ;
    }

    int e = 0, src = 0; float ph = 0.f;
    if (beg < end) {
        e = eidcsr[beg]; src = ei[2 * e]; ph = phi_arr[e];
    }
    for (int idx = beg; idx < end; ++idx) {
        // prefetch next edge's scalars (overlaps current edge's work)
        int e2 = 0, src2 = 0; float ph2 = 0.f;
        if (idx + 1 < end) {
            e2 = eidcsr[idx + 1]; src2 = ei[2 * e2]; ph2 = phi_arr[e2];
        }
        float s1, c1;
        sincosf(ph, &s1, &c1);
        const float c2 = c1 * c1 - s1 * s1;
        const float s2 = 2.0f * c1 * s1;
        if (lane < 16) {                         // stage transported row (80 f32)
            const float* xr = xin + (size_t)src * CQ + lane * 5;
            float v0 = xr[0], v1 = xr[1], v2 = xr[2], v3 = xr[3], v4 = xr[4];
            xts[w][lane * 5 + 0] = v0;
            xts[w][lane * 5 + 1] = c1 * v1 - s1 * v2;
            xts[w][lane * 5 + 2] = s1 * v1 + c1 * v2;
            xts[w][lane * 5 + 3] = c2 * v3 - s2 * v4;
            xts[w][lane * 5 + 4] = s2 * v3 + c2 * v4;
        } else if (lane < 16 + NFR) {            // stage tv (10 f32)
            tvs[w][lane - 16] = pre[(size_t)e * NFR + (lane - 16)];
        }
        // same-wave DS ordering: compiler inserts lgkmcnt wait before reads
        #pragma unroll
        for (int j = 0; j < 12; ++j)
            acc[j] += xts[w][cqi[j]] * tvs[w][fri[j]];
        if (lane < 32)                           // k = lane+768 < 800
            acc[12] += xts[w][cqi[12]] * tvs[w][fri[12]];
        e = e2; src = src2; ph = ph2;
    }

    unsigned short* ar = Agg + (size_t)n * KTOT;
    #pragma unroll
    for (int j = 0; j < 12; ++j) ar[lane + 64 * j] = f2h_u(acc[j]);
    if (lane < 32) ar[lane + 768] = f2h_u(acc[12]);
}

// ---------------------------------------------------------------------------
// Self-interaction + bias (fp32): y[n,op] = sum_cq x[n,cq]*Ws[o,c,p,q] + (p==0)b[o]
// Full write — serves as init before node_gemm's +=.
// ---------------------------------------------------------------------------
__global__ void selfint(const float* __restrict__ xin, const float* __restrict__ Ws,
                        const float* __restrict__ b, float* __restrict__ y) {
    __shared__ float ws_s[NC * NC * NQ * NQ];  // 25.6 KB
    int tid = threadIdx.x;
    for (int i = tid; i < NC * NC * NQ * NQ; i += blockDim.x) ws_s[i] = Ws[i];
    __syncthreads();
    int idx = blockIdx.x * blockDim.x + tid;     // over N*80
    if (idx >= NN * OP) return;
    int n = idx / OP, op = idx % OP;
    int o = op / NQ, p = op % NQ;
    const float* xrow = xin + n * CQ;
    float acc = (p == 0) ? b[o] : 0.0f;
    #pragma unroll
    for (int c = 0; c < NC; ++c)
        #pragma unroll
        for (int q = 0; q < NQ; ++q)
            acc = fmaf(xrow[c * NQ + q], ws_s[o * 400 + c * 25 + p * 5 + q], acc);
    y[idx] = acc;
}

// ---------------------------------------------------------------------------
// Node GEMM v12: y[n0..n0+16, 0..80) += AggA[16 x 800] @ Wt[800 x 80].
// 5 waves; wave nt holds its B slice in 25 f16x8 regs (W-stationary, loads
// L2-hit). A staged whole (16 x 800 fp16 = 25.6 KB + pad) in one barrier.
// Exclusive node ownership -> plain fp32 += epilogue (NO atomics).
// ---------------------------------------------------------------------------
__global__ __launch_bounds__(320)
void node_gemm(const unsigned short* __restrict__ Agg,
               const unsigned short* __restrict__ Wt,
               float* __restrict__ y) {
    __shared__ __align__(16) unsigned short A_s[16 * APAD];  // 25,856 B
    const int tid = threadIdx.x;
    const int nt = tid >> 6, lane = tid & 63;
    const int lrow = lane & 15, quad = lane >> 4;
    const int n0 = blockIdx.x * 16;              // NN = 625*16 exactly

    const f16x8* __restrict__ wf = (const f16x8*)Wt;
    f16x8 breg[25];
    #pragma unroll
    for (int ks = 0; ks < 25; ++ks)
        breg[ks] = wf[(ks * 5 + nt) * 64 + lane];

    // stage A: 16 rows x 1600 B = 1600 x 16B chunks; 320 thr x 5
    {
        const uint4* srcp = (const uint4*)(Agg + (size_t)n0 * KTOT);
        #pragma unroll
        for (int i = 0; i < 5; ++i) {
            int li = tid + 320 * i;              // 0..1599
            int row = li / 100, c16 = li % 100;
            *(uint4*)(&A_s[row * APAD + c16 * 8]) = srcp[row * 100 + c16];
        }
    }
    __syncthreads();

    f32x4 acc = (f32x4){0.f, 0.f, 0.f, 0.f};
    #pragma unroll
    for (int ks = 0; ks < 25; ++ks) {
        f16x8 a = *(const f16x8*)(&A_s[lrow * APAD + 32 * ks + 8 * quad]);
        acc = __builtin_amdgcn_mfma_f32_16x16x32_f16(a, breg[ks], acc, 0, 0, 0);
    }

    // D[m=node][n=op]: col=lane&15 -> op-in-tile, row=quad*4+r -> node-in-tile
    #pragma unroll
    for (int r = 0; r < 4; ++r) {
        float* yp = y + (size_t)(n0 + quad * 4 + r) * OP + 16 * nt + lrow;
        *yp += acc[r];
    }
}

// ---------------------------------------------------------------------------
// Regular nonlinearity (+ optional residual). One thread per (n,c).
// ---------------------------------------------------------------------------
__global__ void nonlin(const float* __restrict__ yin, const float* __restrict__ res,
                       float* __restrict__ out) {
    int idx = blockIdx.x * blockDim.x + threadIdx.x;  // over N*C
    if (idx >= NN * NC) return;
    const float* vp = yin + (long long)idx * NQ;
    float a0 = vp[0], a1 = vp[1], a2 = vp[2], a3 = vp[3], a4 = vp[4];
    if (res != nullptr) {
        const float* rp = res + (long long)idx * NQ;
        a0 += rp[0]; a1 += rp[1]; a2 += rp[2]; a3 += rp[3]; a4 += rp[4];
    }
    float o0 = 0.f, o1 = 0.f, o2 = 0.f, o3 = 0.f, o4 = 0.f;
    #pragma unroll
    for (int k = 0; k < 7; ++k) {
        float th = (float)(2.0 * M_PI / 7.0) * (float)k;
        float c1k = cosf(th), s1k = sinf(th);
        float c2k = cosf(2.0f * th), s2k = sinf(2.0f * th);
        float s = a0 + a1 * c1k + a2 * s1k + a3 * c2k + a4 * s2k;
        s = fmaxf(s, 0.0f);
        o0 += s;
        o1 += s * c1k; o2 += s * s1k;
        o3 += s * c2k; o4 += s * s2k;
    }
    const float i7 = 1.0f / 7.0f, t7 = 2.0f / 7.0f;
    float* op = out + (long long)idx * NQ;
    op[0] = o0 * i7;
    op[1] = o1 * t7; op[2] = o2 * t7;
    op[3] = o3 * t7; op[4] = o4 * t7;
}

// ---------------------------------------------------------------------------
extern "C" void kernel_launch(void* const* d_in, const int* in_sizes, int n_in,
                              void* d_out, int out_size, void* d_ws, size_t ws_size,
                              hipStream_t stream) {
    const float* x    = (const float*)d_in[0];
    const int*   ei   = (const int*)d_in[1];      // int inputs arrive as int32
    const float* pre  = (const float*)d_in[2];
    const float* phi  = (const float*)d_in[3];
    const float* W1   = (const float*)d_in[4];
    const float* b1   = (const float*)d_in[5];
    const float* Ws1  = (const float*)d_in[6];
    const float* W2   = (const float*)d_in[7];
    const float* b2   = (const float*)d_in[8];
    const float* Ws2  = (const float*)d_in[9];
    float* out = (float*)d_out;

    // Workspace layout (~23.4 MB)
    unsigned short* Wt1 = (unsigned short*)d_ws;          // 128 KB
    unsigned short* Wt2 = Wt1 + WSZ;                      // 128 KB
    float* y1 = (float*)(Wt2 + WSZ);                      // 3.2 MB
    float* h  = y1 + (size_t)NN * OP;                     // 3.2 MB
    unsigned short* Agg = (unsigned short*)(h + (size_t)NN * OP);  // 16 MB
    int* cnt    = (int*)(Agg + (size_t)NN * KTOT);        // 40 KB
    int* offs   = cnt + NN;                               // 40 KB
    int* cursor = offs + NN + 1;                          // 40 KB
    int* eidcsr = cursor + NN;                            // 640 KB

    reorder_wt<<<(WSZ + 255) / 256, 256, 0, stream>>>(W1, W2, Wt1, Wt2);

    // CSR build (once; serves both layers)
    hipMemsetAsync(cnt, 0, NN * sizeof(int), stream);
    csr_hist<<<(NE + 255) / 256, 256, 0, stream>>>(ei, cnt);
    csr_scan<<<1, 256, 0, stream>>>(cnt, offs, cursor);
    csr_place<<<(NE + 255) / 256, 256, 0, stream>>>(ei, cursor, eidcsr);

    // Layer 1
    aggregate<<<NN / 4, 256, 0, stream>>>(x, ei, pre, phi, offs, eidcsr, Agg);
    selfint<<<(NN * OP + 255) / 256, 256, 0, stream>>>(x, Ws1, b1, y1);
    node_gemm<<<NN / 16, 320, 0, stream>>>(Agg, Wt1, y1);
    nonlin<<<(NN * NC + 255) / 256, 256, 0, stream>>>(y1, nullptr, h);

    // Layer 2
    aggregate<<<NN / 4, 256, 0, stream>>>(h, ei, pre, phi, offs, eidcsr, Agg);
    selfint<<<(NN * OP + 255) / 256, 256, 0, stream>>>(h, Ws2, b2, y1);
    node_gemm<<<NN / 16, 320, 0, stream>>>(Agg, Wt2, y1);
    nonlin<<<(NN * NC + 255) / 256, 256, 0, stream>>>(y1, x, out);
}

// Round 3
// 255.319 us; speedup vs baseline: 1.3471x; 1.2359x over previous
//
#include <hip/hip_runtime.h>
#include <hip/hip_bf16.h>
#include <hip/hip_fp16.h>
#include <math.h>

#ifndef M_PI
#define M_PI 3.14159265358979323846
#endif

// Problem constants
#define NN 10000      // nodes
#define NE 160000     // edges
#define NC 16         // channels
#define NQ 5          // 2*order+1
#define NFR 10        // N_FREQ * N_RINGS
#define CQ 80         // NC*NQ
#define OP 80         // outputs per node

// Extended GEMM: k in [0,800) edge-aggregate part with k = cq*10 + fr;
//                k in [800,880) self-interaction part with k = 800 + cq;
//                k in [880,896) zero pad (both A and B written as 0).
#define KTOT2 896
#define KS 28         // 896 / 32 MFMA k-steps
#define WTN 71680     // KTOT2 * 80 weight elements per layer
#define APAD 936      // LDS row stride fp16: 468 dwords = 20 mod 32 banks (v12-proven residue)

typedef __attribute__((ext_vector_type(8))) _Float16 f16x8;
typedef __attribute__((ext_vector_type(4))) float f32x4;

static __device__ __forceinline__ unsigned short f2h_u(float f) {
    return __builtin_bit_cast(unsigned short, (_Float16)f);
}
static __device__ __forceinline__ unsigned pack2h(float lo, float hi) {
    return (unsigned)f2h_u(lo) | ((unsigned)f2h_u(hi) << 16);
}

// ---------------------------------------------------------------------------
// prep_all: one pass over edges does (a) CSR degree histogram, (b) per-edge
// rotation table rot4[e] = (c1, s1, c2, s2)  [kills the 80x-redundant sincos
// in the old aggregate]; threads i < WTN also (c) reorder W+Ws into MFMA-B
// fragment order:
//   Wt[((ks*5+nt)*64 + lane)*8 + j] = fp16 of B[k][n], n = 16*nt + (lane&15),
//   k = 32*ks + 8*(lane>>4) + j, with the k-map documented above.
// ---------------------------------------------------------------------------
__global__ void prep_all(const int* __restrict__ ei, const float* __restrict__ phi,
                         const float* __restrict__ W1, const float* __restrict__ Ws1,
                         const float* __restrict__ W2, const float* __restrict__ Ws2,
                         int* __restrict__ cnt, float4* __restrict__ rot4,
                         unsigned short* __restrict__ Wt1, unsigned short* __restrict__ Wt2) {
    int i = blockIdx.x * blockDim.x + threadIdx.x;
    if (i < NE) {
        atomicAdd(&cnt[ei[2 * i + 1]], 1);
        float s1, c1;
        sincosf(phi[i], &s1, &c1);
        rot4[i] = make_float4(c1, s1, c1 * c1 - s1 * s1, 2.0f * c1 * s1);
    }
    if (i < WTN) {
        int j    = i & 7;
        int lane = (i >> 3) & 63;
        int grp  = i >> 9;            // 0..139 = ks*5 + nt
        int ks   = grp / 5;
        int nt   = grp % 5;
        int quad = lane >> 4;
        int lrow = lane & 15;
        int n    = 16 * nt + lrow;    // output index op
        int k    = 32 * ks + 8 * quad + j;
        int o = n / 5, p = n % 5;
        float v1, v2;
        if (k < 800) {                // edge part: k = cq*10 + fr
            int cq = k / 10, fr = k % 10;
            int c = cq / 5, q = cq % 5;
            int f = fr >> 1, r = fr & 1;
            int src = ((((o * NC + c) * NQ + p) * NQ + q) * 5 + f) * 2 + r;
            v1 = W1[src]; v2 = W2[src];
        } else if (k < 880) {         // self part: k = 800 + cq
            int cq = k - 800;
            int c = cq / 5, q = cq % 5;
            int src = ((o * NC + c) * NQ + p) * NQ + q;
            v1 = Ws1[src]; v2 = Ws2[src];
        } else {                      // pad
            v1 = 0.0f; v2 = 0.0f;
        }
        Wt1[i] = f2h_u(v1); Wt2[i] = f2h_u(v2);
    }
}

// ---------------------------------------------------------------------------
// CSR scan: 1 block, 1024 threads, 10 counts each (1000 active) + LDS scan.
// ---------------------------------------------------------------------------
__global__ void csr_scan(const int* __restrict__ cnt, int* __restrict__ offs,
                         int* __restrict__ cursor) {
    __shared__ int part[1024];
    const int t = threadIdx.x;
    const int b0 = t * 10;
    int s = 0;
    if (t < 1000)
        for (int i = 0; i < 10; ++i) s += cnt[b0 + i];
    part[t] = s;
    __syncthreads();
    for (int d = 1; d < 1024; d <<= 1) {
        int u = (t >= d) ? part[t - d] : 0;
        __syncthreads();
        part[t] += u;
        __syncthreads();
    }
    if (t < 1000) {
        int run = (t == 0) ? 0 : part[t - 1];
        for (int i = 0; i < 10; ++i) {
            offs[b0 + i] = run;
            cursor[b0 + i] = run;
            run += cnt[b0 + i];
        }
    }
    if (t == 1023) offs[NN] = part[1023];    // = NE
}

__global__ void csr_place(const int* __restrict__ ei, int* __restrict__ cursor,
                          int* __restrict__ eidcsr) {
    int e = blockIdx.x * blockDim.x + threadIdx.x;
    if (e < NE) {
        int pos = atomicAdd(&cursor[ei[2 * e + 1]], 1);
        eidcsr[pos] = e;
    }
}

// ---------------------------------------------------------------------------
// Aggregate v13: one thread per (node, cq). 80 threads/node, block = 4 nodes.
// acc[fr] (10 regs) accumulates sum_e xt[e,cq] * tv[e,fr] in fp32, CSR order
// (same accumulation order + transport math as verified v12). ZERO LDS in the
// loop; all per-edge data via L2-broadcast loads (rot4, tv) and coalesced
// team gathers (x[src]). ~48 VGPR -> ~30 waves/CU; latency hidden by TLP +
// 1-deep (e,src) prefetch. Writes the extended-K A row:
//   Agg[n][cq*10+fr] = fp16(acc[fr]);  Agg[n][800+cq] = fp16(x[n][cq]);
//   Agg[n][880..896) = 0  (pad, re-poison-safe).
// ---------------------------------------------------------------------------
__global__ __launch_bounds__(320)
void aggregate(const float* __restrict__ xin, const int* __restrict__ ei,
               const float* __restrict__ pre, const float4* __restrict__ rot4,
               const int* __restrict__ offs, const int* __restrict__ eidcsr,
               unsigned short* __restrict__ Agg) {
    const int tid = threadIdx.x;
    const int ln  = tid / 80;            // local node 0..3
    const int cq  = tid - ln * 80;
    const int n   = blockIdx.x * 4 + ln; // NN = 2500*4 exactly
    const int q   = cq % 5;
    // transport partner: q=1<->2, q=3<->4; q=0 self
    const int qp   = (q == 0) ? 0 : ((q & 1) ? q + 1 : q - 1);
    const int pofs = cq - q + qp;
    const bool is0 = (q == 0);
    const bool hi  = (q >= 3);           // order-2 pair
    const float sgn = (q == 1 || q == 3) ? -1.0f : 1.0f;

    const int beg = offs[n], end = offs[n + 1];

    float acc[10];
    #pragma unroll
    for (int f = 0; f < 10; ++f) acc[f] = 0.0f;

    int e = 0, src = 0;
    if (beg < end) { e = eidcsr[beg]; src = ei[2 * e]; }
    for (int idx = beg; idx < end; ++idx) {
        int e2 = 0, src2 = 0;
        if (idx + 1 < end) { e2 = eidcsr[idx + 1]; src2 = ei[2 * e2]; }
        const float4 rt = rot4[e];
        const float* xr = xin + (size_t)src * CQ;
        const float xa = xr[cq];
        const float xb = xr[pofs];
        const float* tp = pre + (size_t)e * NFR;
        const float2 t0 = *(const float2*)(tp + 0);
        const float2 t1 = *(const float2*)(tp + 2);
        const float2 t2 = *(const float2*)(tp + 4);
        const float2 t3 = *(const float2*)(tp + 6);
        const float2 t4 = *(const float2*)(tp + 8);
        // xt = A*xa + B*xb reproduces v12's transport exactly:
        // q=0: xa; q=1: c1*xa - s1*xb; q=2: c1*xa + s1*xb (xa=row2,xb=row1)
        // q=3: c2*xa - s2*xb; q=4: c2*xa + s2*xb
        const float Ac = is0 ? 1.0f : (hi ? rt.z : rt.x);
        const float Bc = is0 ? 0.0f : sgn * (hi ? rt.w : rt.y);
        const float xt = Ac * xa + Bc * xb;
        acc[0] += xt * t0.x;  acc[1] += xt * t0.y;
        acc[2] += xt * t1.x;  acc[3] += xt * t1.y;
        acc[4] += xt * t2.x;  acc[5] += xt * t2.y;
        acc[6] += xt * t3.x;  acc[7] += xt * t3.y;
        acc[8] += xt * t4.x;  acc[9] += xt * t4.y;
        e = e2; src = src2;
    }

    unsigned* arw = (unsigned*)(Agg + (size_t)n * KTOT2 + cq * 10);  // 4B-aligned
    arw[0] = pack2h(acc[0], acc[1]);
    arw[1] = pack2h(acc[2], acc[3]);
    arw[2] = pack2h(acc[4], acc[5]);
    arw[3] = pack2h(acc[6], acc[7]);
    arw[4] = pack2h(acc[8], acc[9]);
    // self-interaction A part + zero pad
    Agg[(size_t)n * KTOT2 + 800 + cq] = f2h_u(xin[(size_t)n * CQ + cq]);
    if (cq < 16) Agg[(size_t)n * KTOT2 + 880 + cq] = 0;
}

// ---------------------------------------------------------------------------
// Node GEMM v13: y[n0..n0+16, :] = A'[16 x 896] @ B'[896 x 80] + bias.
// A' = [edge-aggregate | x | 0], B' = [Wt | Wst | 0] -> selfint fused, pure
// store (no init kernel, no RMW). 5 waves, wave nt W-stationary in 112 VGPRs.
// ---------------------------------------------------------------------------
__global__ __launch_bounds__(320)
void node_gemm(const unsigned short* __restrict__ Agg,
               const unsigned short* __restrict__ Wt,
               const float* __restrict__ b,
               float* __restrict__ y) {
    __shared__ __align__(16) unsigned short A_s[16 * APAD];  // 29,952 B
    const int tid = threadIdx.x;
    const int nt = tid >> 6, lane = tid & 63;
    const int lrow = lane & 15, quad = lane >> 4;
    const int n0 = blockIdx.x * 16;              // NN = 625*16 exactly

    const f16x8* __restrict__ wf = (const f16x8*)Wt;
    f16x8 breg[KS];
    #pragma unroll
    for (int ks = 0; ks < KS; ++ks)
        breg[ks] = wf[(ks * 5 + nt) * 64 + lane];

    // stage A: 16 rows x 1792 B = 1792 x 16B chunks over 320 threads
    {
        const uint4* srcp = (const uint4*)(Agg + (size_t)n0 * KTOT2);
        #pragma unroll
        for (int i = 0; i < 6; ++i) {
            int li = tid + 320 * i;              // 0..1919, use 0..1791
            if (li < 1792) {
                int row = li / 112, c16 = li % 112;
                *(uint4*)(&A_s[row * APAD + c16 * 8]) = srcp[row * 112 + c16];
            }
        }
    }
    __syncthreads();

    f32x4 acc = (f32x4){0.f, 0.f, 0.f, 0.f};
    #pragma unroll
    for (int ks = 0; ks < KS; ++ks) {
        f16x8 a = *(const f16x8*)(&A_s[lrow * APAD + 32 * ks + 8 * quad]);
        acc = __builtin_amdgcn_mfma_f32_16x16x32_f16(a, breg[ks], acc, 0, 0, 0);
    }

    const int op = 16 * nt + lrow;
    const float bias = (op % 5 == 0) ? b[op / 5] : 0.0f;
    #pragma unroll
    for (int r = 0; r < 4; ++r)
        y[(size_t)(n0 + quad * 4 + r) * OP + op] = acc[r] + bias;
}

// ---------------------------------------------------------------------------
// Regular nonlinearity (+ optional residual). One thread per (n,c).
// (cosf/sinf of compile-time constants -> folded; pure FMA kernel.)
// ---------------------------------------------------------------------------
__global__ void nonlin(const float* __restrict__ yin, const float* __restrict__ res,
                       float* __restrict__ out) {
    int idx = blockIdx.x * blockDim.x + threadIdx.x;  // over N*C
    if (idx >= NN * NC) return;
    const float* vp = yin + (long long)idx * NQ;
    float a0 = vp[0], a1 = vp[1], a2 = vp[2], a3 = vp[3], a4 = vp[4];
    if (res != nullptr) {
        const float* rp = res + (long long)idx * NQ;
        a0 += rp[0]; a1 += rp[1]; a2 += rp[2]; a3 += rp[3]; a4 += rp[4];
    }
    float o0 = 0.f, o1 = 0.f, o2 = 0.f, o3 = 0.f, o4 = 0.f;
    #pragma unroll
    for (int k = 0; k < 7; ++k) {
        float th = (float)(2.0 * M_PI / 7.0) * (float)k;
        float c1k = cosf(th), s1k = sinf(th);
        float c2k = cosf(2.0f * th), s2k = sinf(2.0f * th);
        float s = a0 + a1 * c1k + a2 * s1k + a3 * c2k + a4 * s2k;
        s = fmaxf(s, 0.0f);
        o0 += s;
        o1 += s * c1k; o2 += s * s1k;
        o3 += s * c2k; o4 += s * s2k;
    }
    const float i7 = 1.0f / 7.0f, t7 = 2.0f / 7.0f;
    float* op = out + (long long)idx * NQ;
    op[0] = o0 * i7;
    op[1] = o1 * t7; op[2] = o2 * t7;
    op[3] = o3 * t7; op[4] = o4 * t7;
}

// ---------------------------------------------------------------------------
extern "C" void kernel_launch(void* const* d_in, const int* in_sizes, int n_in,
                              void* d_out, int out_size, void* d_ws, size_t ws_size,
                              hipStream_t stream) {
    const float* x    = (const float*)d_in[0];
    const int*   ei   = (const int*)d_in[1];      // int inputs arrive as int32
    const float* pre  = (const float*)d_in[2];
    const float* phi  = (const float*)d_in[3];
    const float* W1   = (const float*)d_in[4];
    const float* b1   = (const float*)d_in[5];
    const float* Ws1  = (const float*)d_in[6];
    const float* W2   = (const float*)d_in[7];
    const float* b2   = (const float*)d_in[8];
    const float* Ws2  = (const float*)d_in[9];
    float* out = (float*)d_out;

    // Workspace layout (~28 MB)
    unsigned short* Wt1 = (unsigned short*)d_ws;            // 71680 fp16 = 143.4 KB
    unsigned short* Wt2 = Wt1 + WTN;                        // 143.4 KB
    float* y1 = (float*)(Wt2 + WTN);                        // 3.2 MB
    float* h  = y1 + (size_t)NN * OP;                       // 3.2 MB
    unsigned short* Agg = (unsigned short*)(h + (size_t)NN * OP);  // 17.92 MB
    float4* rot4 = (float4*)(Agg + (size_t)NN * KTOT2);     // 2.56 MB
    int* cnt    = (int*)(rot4 + NE);                        // 40 KB
    int* offs   = cnt + NN;                                 // 40 KB
    int* cursor = offs + NN + 1;                            // 40 KB
    int* eidcsr = cursor + NN;                              // 640 KB

    // prep: hist + rot table + W/Ws reorder, one dispatch
    hipMemsetAsync(cnt, 0, NN * sizeof(int), stream);
    prep_all<<<(NE + 255) / 256, 256, 0, stream>>>(ei, phi, W1, Ws1, W2, Ws2,
                                                   cnt, rot4, Wt1, Wt2);
    csr_scan<<<1, 1024, 0, stream>>>(cnt, offs, cursor);
    csr_place<<<(NE + 255) / 256, 256, 0, stream>>>(ei, cursor, eidcsr);

    // Layer 1
    aggregate<<<NN / 4, 320, 0, stream>>>(x, ei, pre, rot4, offs, eidcsr, Agg);
    node_gemm<<<NN / 16, 320, 0, stream>>>(Agg, Wt1, b1, y1);
    nonlin<<<(NN * NC + 255) / 256, 256, 0, stream>>>(y1, nullptr, h);

    // Layer 2
    aggregate<<<NN / 4, 320, 0, stream>>>(h, ei, pre, rot4, offs, eidcsr, Agg);
    node_gemm<<<NN / 16, 320, 0, stream>>>(Agg, Wt2, b2, y1);
    nonlin<<<(NN * NC + 255) / 256, 256, 0, stream>>>(y1, x, out);
}

// Round 4
// 219.341 us; speedup vs baseline: 1.5680x; 1.1640x over previous
//
#include <hip/hip_runtime.h>
#include <hip/hip_bf16.h>
#include <hip/hip_fp16.h>
#include <math.h>

#ifndef M_PI
#define M_PI 3.14159265358979323846
#endif

// Problem constants
#define NN 10000      // nodes
#define NE 160000     // edges
#define NC 16         // channels
#define NQ 5          // 2*order+1
#define NFR 10        // N_FREQ * N_RINGS
#define CQ 80         // NC*NQ
#define OP 80         // outputs per node

// Extended GEMM: k in [0,800) edge-aggregate part with k = cq*10 + fr;
//                k in [800,880) self-interaction part with k = 800 + cq;
//                k in [880,896) zero pad (both A and B written as 0).
#define KTOT2 896
#define KS 28         // 896 / 32 MFMA k-steps
#define WTN 71680     // KTOT2 * 80 weight elements per layer
#define APAD 936      // LDS row stride fp16: 468 dwords = 20 mod 32 banks (v12-proven residue)

typedef __attribute__((ext_vector_type(8))) _Float16 f16x8;
typedef __attribute__((ext_vector_type(4))) float f32x4;

static __device__ __forceinline__ unsigned short f2h_u(float f) {
    return __builtin_bit_cast(unsigned short, (_Float16)f);
}
static __device__ __forceinline__ unsigned pack2h(float lo, float hi) {
    return (unsigned)f2h_u(lo) | ((unsigned)f2h_u(hi) << 16);
}

// ---------------------------------------------------------------------------
// prep_all: (a) CSR degree histogram over edges; (b) threads i < WTN reorder
// W+Ws into MFMA-B fragment order (k-map in header comment). rot table moved
// into csr_place_gather (v14).
// ---------------------------------------------------------------------------
__global__ void prep_all(const int* __restrict__ ei,
                         const float* __restrict__ W1, const float* __restrict__ Ws1,
                         const float* __restrict__ W2, const float* __restrict__ Ws2,
                         int* __restrict__ cnt,
                         unsigned short* __restrict__ Wt1, unsigned short* __restrict__ Wt2) {
    int i = blockIdx.x * blockDim.x + threadIdx.x;
    if (i < NE) atomicAdd(&cnt[ei[2 * i + 1]], 1);
    if (i < WTN) {
        int j    = i & 7;
        int lane = (i >> 3) & 63;
        int grp  = i >> 9;            // 0..139 = ks*5 + nt
        int ks   = grp / 5;
        int nt   = grp % 5;
        int quad = lane >> 4;
        int lrow = lane & 15;
        int n    = 16 * nt + lrow;    // output index op
        int k    = 32 * ks + 8 * quad + j;
        int o = n / 5, p = n % 5;
        float v1, v2;
        if (k < 800) {                // edge part: k = cq*10 + fr
            int cq = k / 10, fr = k % 10;
            int c = cq / 5, q = cq % 5;
            int f = fr >> 1, r = fr & 1;
            int src = ((((o * NC + c) * NQ + p) * NQ + q) * 5 + f) * 2 + r;
            v1 = W1[src]; v2 = W2[src];
        } else if (k < 880) {         // self part: k = 800 + cq
            int cq = k - 800;
            int c = cq / 5, q = cq % 5;
            int src = ((o * NC + c) * NQ + p) * NQ + q;
            v1 = Ws1[src]; v2 = Ws2[src];
        } else {                      // pad
            v1 = 0.0f; v2 = 0.0f;
        }
        Wt1[i] = f2h_u(v1); Wt2[i] = f2h_u(v2);
    }
}

// ---------------------------------------------------------------------------
// CSR scan: 1 block, 1024 threads, 10 counts each (1000 active) + LDS scan.
// ---------------------------------------------------------------------------
__global__ void csr_scan(const int* __restrict__ cnt, int* __restrict__ offs,
                         int* __restrict__ cursor) {
    __shared__ int part[1024];
    const int t = threadIdx.x;
    const int b0 = t * 10;
    int s = 0;
    if (t < 1000)
        for (int i = 0; i < 10; ++i) s += cnt[b0 + i];
    part[t] = s;
    __syncthreads();
    for (int d = 1; d < 1024; d <<= 1) {
        int u = (t >= d) ? part[t - d] : 0;
        __syncthreads();
        part[t] += u;
        __syncthreads();
    }
    if (t < 1000) {
        int run = (t == 0) ? 0 : part[t - 1];
        for (int i = 0; i < 10; ++i) {
            offs[b0 + i] = run;
            cursor[b0 + i] = run;
            run += cnt[b0 + i];
        }
    }
    if (t == 1023) offs[NN] = part[1023];    // = NE
}

// ---------------------------------------------------------------------------
// csr_place_gather (v14): each edge claims its CSR slot AND writes the
// aggregate kernel's entire per-edge working set there, in STREAM layout:
//   srcs[pos] = ei[2e];  recs[pos] = {tv[0..9], c1, s1}  (48 B, 3 x float4)
// Reads (ei, phi, pre) are all sequential in e; scattered 48B writes are
// fire-and-forget. This removes the eidcsr->ei->x dependent chain and the
// random-order pre/rot reads that made v13's aggregate latency-bound.
// ---------------------------------------------------------------------------
__global__ void csr_place_gather(const int* __restrict__ ei, const float* __restrict__ phi,
                                 const float* __restrict__ pre,
                                 int* __restrict__ cursor,
                                 int* __restrict__ srcs, float4* __restrict__ recs) {
    int e = blockIdx.x * blockDim.x + threadIdx.x;
    if (e >= NE) return;
    const int dst = ei[2 * e + 1];
    const int srcn = ei[2 * e];
    const int pos = atomicAdd(&cursor[dst], 1);
    float s1, c1;
    sincosf(phi[e], &s1, &c1);
    const float* tp = pre + (size_t)e * NFR;
    float4* rp = recs + (size_t)pos * 3;
    rp[0] = make_float4(tp[0], tp[1], tp[2], tp[3]);
    rp[1] = make_float4(tp[4], tp[5], tp[6], tp[7]);
    rp[2] = make_float4(tp[8], tp[9], c1, s1);
    srcs[pos] = srcn;
}

// ---------------------------------------------------------------------------
// Aggregate v14: one thread per (node, cq); acc[fr] in 10 regs, fp32, CSR
// order (same accumulation order + transport math as v13). All per-edge data
// now SEQUENTIAL streams (srcs, recs); only x[src] is a gather (L2-resident,
// 3.2 MB). Edge loop unrolled x2 -> ~12 independent loads in flight.
// c2,s2 derived from (c1,s1) per thread (identical values to v13's rot4).
// Writes extended-K A row: Agg[n][cq*10+fr], Agg[n][800+cq]=x[n][cq], pad 0.
// ---------------------------------------------------------------------------
__global__ __launch_bounds__(320)
void aggregate(const float* __restrict__ xin, const int* __restrict__ srcs,
               const float4* __restrict__ recs, const int* __restrict__ offs,
               unsigned short* __restrict__ Agg) {
    const int tid = threadIdx.x;
    const int ln  = tid / 80;            // local node 0..3
    const int cq  = tid - ln * 80;
    const int n   = blockIdx.x * 4 + ln; // NN = 2500*4 exactly
    const int q   = cq % 5;
    // transport partner: q=1<->2, q=3<->4; q=0 self
    const int qp   = (q == 0) ? 0 : ((q & 1) ? q + 1 : q - 1);
    const int pofs = cq - q + qp;
    const bool is0 = (q == 0);
    const bool hi  = (q >= 3);           // order-2 pair
    const float sgn = (q == 1 || q == 3) ? -1.0f : 1.0f;

    const int beg = offs[n], end = offs[n + 1];

    float acc[10];
    #pragma unroll
    for (int f = 0; f < 10; ++f) acc[f] = 0.0f;

#define EDGE_FMA(r0, r1, r2, xa, xb)                                          \
    do {                                                                      \
        const float c1 = (r2).z, s1 = (r2).w;                                 \
        const float c2 = c1 * c1 - s1 * s1;                                   \
        const float s2 = 2.0f * c1 * s1;                                      \
        const float Ac = is0 ? 1.0f : (hi ? c2 : c1);                         \
        const float Bc = is0 ? 0.0f : sgn * (hi ? s2 : s1);                   \
        const float xt = Ac * (xa) + Bc * (xb);                               \
        acc[0] += xt * (r0).x;  acc[1] += xt * (r0).y;                        \
        acc[2] += xt * (r0).z;  acc[3] += xt * (r0).w;                        \
        acc[4] += xt * (r1).x;  acc[5] += xt * (r1).y;                        \
        acc[6] += xt * (r1).z;  acc[7] += xt * (r1).w;                        \
        acc[8] += xt * (r2).x;  acc[9] += xt * (r2).y;                        \
    } while (0)

    int idx = beg;
    for (; idx + 2 <= end; idx += 2) {
        const int sA = srcs[idx];
        const int sB = srcs[idx + 1];
        const float4* rA = recs + (size_t)idx * 3;
        const float4 a0 = rA[0], a1 = rA[1], a2 = rA[2];
        const float4 b0 = rA[3], b1 = rA[4], b2 = rA[5];
        const float* xrA = xin + (size_t)sA * CQ;
        const float* xrB = xin + (size_t)sB * CQ;
        const float xaA = xrA[cq], xbA = xrA[pofs];
        const float xaB = xrB[cq], xbB = xrB[pofs];
        EDGE_FMA(a0, a1, a2, xaA, xbA);
        EDGE_FMA(b0, b1, b2, xaB, xbB);
    }
    if (idx < end) {
        const int sA = srcs[idx];
        const float4* rA = recs + (size_t)idx * 3;
        const float4 a0 = rA[0], a1 = rA[1], a2 = rA[2];
        const float* xrA = xin + (size_t)sA * CQ;
        const float xaA = xrA[cq], xbA = xrA[pofs];
        EDGE_FMA(a0, a1, a2, xaA, xbA);
    }
#undef EDGE_FMA

    unsigned* arw = (unsigned*)(Agg + (size_t)n * KTOT2 + cq * 10);  // 4B-aligned
    arw[0] = pack2h(acc[0], acc[1]);
    arw[1] = pack2h(acc[2], acc[3]);
    arw[2] = pack2h(acc[4], acc[5]);
    arw[3] = pack2h(acc[6], acc[7]);
    arw[4] = pack2h(acc[8], acc[9]);
    // self-interaction A part + zero pad
    Agg[(size_t)n * KTOT2 + 800 + cq] = f2h_u(xin[(size_t)n * CQ + cq]);
    if (cq < 16) Agg[(size_t)n * KTOT2 + 880 + cq] = 0;
}

// ---------------------------------------------------------------------------
// Node GEMM: y[n0..n0+16, :] = A'[16 x 896] @ B'[896 x 80] + bias.
// A' = [edge-aggregate | x | 0], B' = [Wt | Wst | 0] -> selfint fused, pure
// store. 5 waves, wave nt W-stationary in 112 VGPRs.
// ---------------------------------------------------------------------------
__global__ __launch_bounds__(320)
void node_gemm(const unsigned short* __restrict__ Agg,
               const unsigned short* __restrict__ Wt,
               const float* __restrict__ b,
               float* __restrict__ y) {
    __shared__ __align__(16) unsigned short A_s[16 * APAD];  // 29,952 B
    const int tid = threadIdx.x;
    const int nt = tid >> 6, lane = tid & 63;
    const int lrow = lane & 15, quad = lane >> 4;
    const int n0 = blockIdx.x * 16;              // NN = 625*16 exactly

    const f16x8* __restrict__ wf = (const f16x8*)Wt;
    f16x8 breg[KS];
    #pragma unroll
    for (int ks = 0; ks < KS; ++ks)
        breg[ks] = wf[(ks * 5 + nt) * 64 + lane];

    // stage A: 16 rows x 1792 B = 1792 x 16B chunks over 320 threads
    {
        const uint4* srcp = (const uint4*)(Agg + (size_t)n0 * KTOT2);
        #pragma unroll
        for (int i = 0; i < 6; ++i) {
            int li = tid + 320 * i;              // 0..1919, use 0..1791
            if (li < 1792) {
                int row = li / 112, c16 = li % 112;
                *(uint4*)(&A_s[row * APAD + c16 * 8]) = srcp[row * 112 + c16];
            }
        }
    }
    __syncthreads();

    f32x4 acc = (f32x4){0.f, 0.f, 0.f, 0.f};
    #pragma unroll
    for (int ks = 0; ks < KS; ++ks) {
        f16x8 a = *(const f16x8*)(&A_s[lrow * APAD + 32 * ks + 8 * quad]);
        acc = __builtin_amdgcn_mfma_f32_16x16x32_f16(a, breg[ks], acc, 0, 0, 0);
    }

    const int op = 16 * nt + lrow;
    const float bias = (op % 5 == 0) ? b[op / 5] : 0.0f;
    #pragma unroll
    for (int r = 0; r < 4; ++r)
        y[(size_t)(n0 + quad * 4 + r) * OP + op] = acc[r] + bias;
}

// ---------------------------------------------------------------------------
// Regular nonlinearity (+ optional residual). One thread per (n,c).
// ---------------------------------------------------------------------------
__global__ void nonlin(const float* __restrict__ yin, const float* __restrict__ res,
                       float* __restrict__ out) {
    int idx = blockIdx.x * blockDim.x + threadIdx.x;  // over N*C
    if (idx >= NN * NC) return;
    const float* vp = yin + (long long)idx * NQ;
    float a0 = vp[0], a1 = vp[1], a2 = vp[2], a3 = vp[3], a4 = vp[4];
    if (res != nullptr) {
        const float* rp = res + (long long)idx * NQ;
        a0 += rp[0]; a1 += rp[1]; a2 += rp[2]; a3 += rp[3]; a4 += rp[4];
    }
    float o0 = 0.f, o1 = 0.f, o2 = 0.f, o3 = 0.f, o4 = 0.f;
    #pragma unroll
    for (int k = 0; k < 7; ++k) {
        float th = (float)(2.0 * M_PI / 7.0) * (float)k;
        float c1k = cosf(th), s1k = sinf(th);
        float c2k = cosf(2.0f * th), s2k = sinf(2.0f * th);
        float s = a0 + a1 * c1k + a2 * s1k + a3 * c2k + a4 * s2k;
        s = fmaxf(s, 0.0f);
        o0 += s;
        o1 += s * c1k; o2 += s * s1k;
        o3 += s * c2k; o4 += s * s2k;
    }
    const float i7 = 1.0f / 7.0f, t7 = 2.0f / 7.0f;
    float* op = out + (long long)idx * NQ;
    op[0] = o0 * i7;
    op[1] = o1 * t7; op[2] = o2 * t7;
    op[3] = o3 * t7; op[4] = o4 * t7;
}

// ---------------------------------------------------------------------------
extern "C" void kernel_launch(void* const* d_in, const int* in_sizes, int n_in,
                              void* d_out, int out_size, void* d_ws, size_t ws_size,
                              hipStream_t stream) {
    const float* x    = (const float*)d_in[0];
    const int*   ei   = (const int*)d_in[1];      // int inputs arrive as int32
    const float* pre  = (const float*)d_in[2];
    const float* phi  = (const float*)d_in[3];
    const float* W1   = (const float*)d_in[4];
    const float* b1   = (const float*)d_in[5];
    const float* Ws1  = (const float*)d_in[6];
    const float* W2   = (const float*)d_in[7];
    const float* b2   = (const float*)d_in[8];
    const float* Ws2  = (const float*)d_in[9];
    float* out = (float*)d_out;

    // Workspace layout (~33 MB)
    unsigned short* Wt1 = (unsigned short*)d_ws;            // 143.4 KB
    unsigned short* Wt2 = Wt1 + WTN;                        // 143.4 KB
    float* y1 = (float*)(Wt2 + WTN);                        // 3.2 MB
    float* h  = y1 + (size_t)NN * OP;                       // 3.2 MB
    unsigned short* Agg = (unsigned short*)(h + (size_t)NN * OP);  // 17.92 MB
    float4* recs = (float4*)(Agg + (size_t)NN * KTOT2);     // 7.68 MB (16B aligned)
    int* srcs   = (int*)(recs + (size_t)NE * 3);            // 640 KB
    int* cnt    = srcs + NE;                                // 40 KB
    int* offs   = cnt + NN;                                 // 40 KB
    int* cursor = offs + NN + 1;                            // 40 KB

    // prep: hist + W/Ws reorder; scan; place+gather (stream-ordered records)
    hipMemsetAsync(cnt, 0, NN * sizeof(int), stream);
    prep_all<<<(NE + 255) / 256, 256, 0, stream>>>(ei, W1, Ws1, W2, Ws2, cnt, Wt1, Wt2);
    csr_scan<<<1, 1024, 0, stream>>>(cnt, offs, cursor);
    csr_place_gather<<<(NE + 255) / 256, 256, 0, stream>>>(ei, phi, pre, cursor, srcs, recs);

    // Layer 1
    aggregate<<<NN / 4, 320, 0, stream>>>(x, srcs, recs, offs, Agg);
    node_gemm<<<NN / 16, 320, 0, stream>>>(Agg, Wt1, b1, y1);
    nonlin<<<(NN * NC + 255) / 256, 256, 0, stream>>>(y1, nullptr, h);

    // Layer 2
    aggregate<<<NN / 4, 320, 0, stream>>>(h, srcs, recs, offs, Agg);
    node_gemm<<<NN / 16, 320, 0, stream>>>(Agg, Wt2, b2, y1);
    nonlin<<<(NN * NC + 255) / 256, 256, 0, stream>>>(y1, x, out);
}

// Round 5
// 210.456 us; speedup vs baseline: 1.6342x; 1.0422x over previous
//
#include <hip/hip_runtime.h>
#include <hip/hip_bf16.h>
#include <hip/hip_fp16.h>
#include <math.h>

#ifndef M_PI
#define M_PI 3.14159265358979323846
#endif

// Problem constants
#define NN 10000      // nodes
#define NE 160000     // edges
#define NC 16         // channels
#define NQ 5          // 2*order+1
#define NFR 10        // N_FREQ * N_RINGS
#define CQ 80         // NC*NQ
#define OP 80         // outputs per node

// Extended GEMM: k in [0,800) edge-aggregate part with k = cq*10 + fr;
//                k in [800,880) self-interaction part with k = 800 + cq;
//                k in [880,896) zero pad (both A and B written as 0).
#define KTOT2 896
#define KS 28         // 896 / 32 MFMA k-steps
#define WTN 71680     // KTOT2 * 80 weight elements per layer
#define APAD 936      // LDS row stride fp16: 468 dwords = 20 mod 32 banks (v12-proven residue)

typedef __attribute__((ext_vector_type(8))) _Float16 f16x8;
typedef __attribute__((ext_vector_type(4))) float f32x4;

static __device__ __forceinline__ unsigned short f2h_u(float f) {
    return __builtin_bit_cast(unsigned short, (_Float16)f);
}
static __device__ __forceinline__ unsigned pack2h(float lo, float hi) {
    return (unsigned)f2h_u(lo) | ((unsigned)f2h_u(hi) << 16);
}

// ---------------------------------------------------------------------------
// prep_all: (a) CSR degree histogram over edges; (b) threads i < WTN reorder
// W+Ws into MFMA-B fragment order (k-map in header comment).
// ---------------------------------------------------------------------------
__global__ void prep_all(const int* __restrict__ ei,
                         const float* __restrict__ W1, const float* __restrict__ Ws1,
                         const float* __restrict__ W2, const float* __restrict__ Ws2,
                         int* __restrict__ cnt,
                         unsigned short* __restrict__ Wt1, unsigned short* __restrict__ Wt2) {
    int i = blockIdx.x * blockDim.x + threadIdx.x;
    if (i < NE) atomicAdd(&cnt[ei[2 * i + 1]], 1);
    if (i < WTN) {
        int j    = i & 7;
        int lane = (i >> 3) & 63;
        int grp  = i >> 9;            // 0..139 = ks*5 + nt
        int ks   = grp / 5;
        int nt   = grp % 5;
        int quad = lane >> 4;
        int lrow = lane & 15;
        int n    = 16 * nt + lrow;    // output index op
        int k    = 32 * ks + 8 * quad + j;
        int o = n / 5, p = n % 5;
        float v1, v2;
        if (k < 800) {                // edge part: k = cq*10 + fr
            int cq = k / 10, fr = k % 10;
            int c = cq / 5, q = cq % 5;
            int f = fr >> 1, r = fr & 1;
            int src = ((((o * NC + c) * NQ + p) * NQ + q) * 5 + f) * 2 + r;
            v1 = W1[src]; v2 = W2[src];
        } else if (k < 880) {         // self part: k = 800 + cq
            int cq = k - 800;
            int c = cq / 5, q = cq % 5;
            int src = ((o * NC + c) * NQ + p) * NQ + q;
            v1 = Ws1[src]; v2 = Ws2[src];
        } else {                      // pad
            v1 = 0.0f; v2 = 0.0f;
        }
        Wt1[i] = f2h_u(v1); Wt2[i] = f2h_u(v2);
    }
}

// ---------------------------------------------------------------------------
// CSR scan: 1 block, 1024 threads, 10 counts each (1000 active) + LDS scan.
// ---------------------------------------------------------------------------
__global__ void csr_scan(const int* __restrict__ cnt, int* __restrict__ offs,
                         int* __restrict__ cursor) {
    __shared__ int part[1024];
    const int t = threadIdx.x;
    const int b0 = t * 10;
    int s = 0;
    if (t < 1000)
        for (int i = 0; i < 10; ++i) s += cnt[b0 + i];
    part[t] = s;
    __syncthreads();
    for (int d = 1; d < 1024; d <<= 1) {
        int u = (t >= d) ? part[t - d] : 0;
        __syncthreads();
        part[t] += u;
        __syncthreads();
    }
    if (t < 1000) {
        int run = (t == 0) ? 0 : part[t - 1];
        for (int i = 0; i < 10; ++i) {
            offs[b0 + i] = run;
            cursor[b0 + i] = run;
            run += cnt[b0 + i];
        }
    }
    if (t == 1023) offs[NN] = part[1023];    // = NE
}

// ---------------------------------------------------------------------------
// csr_place_gather: each edge claims its CSR slot AND writes the aggregate
// kernel's per-edge working set there in STREAM layout:
//   srcs[pos] = ei[2e];  recs[pos] = {tv[0..9], c1, s1}  (48 B, 3 x float4)
// ---------------------------------------------------------------------------
__global__ void csr_place_gather(const int* __restrict__ ei, const float* __restrict__ phi,
                                 const float* __restrict__ pre,
                                 int* __restrict__ cursor,
                                 int* __restrict__ srcs, float4* __restrict__ recs) {
    int e = blockIdx.x * blockDim.x + threadIdx.x;
    if (e >= NE) return;
    const int dst = ei[2 * e + 1];
    const int srcn = ei[2 * e];
    const int pos = atomicAdd(&cursor[dst], 1);
    float s1, c1;
    sincosf(phi[e], &s1, &c1);
    const float* tp = pre + (size_t)e * NFR;
    float4* rp = recs + (size_t)pos * 3;
    rp[0] = make_float4(tp[0], tp[1], tp[2], tp[3]);
    rp[1] = make_float4(tp[4], tp[5], tp[6], tp[7]);
    rp[2] = make_float4(tp[8], tp[9], c1, s1);
    srcs[pos] = srcn;
}

// ---------------------------------------------------------------------------
// Aggregate v15: one thread per (node, cq); acc[fr] in 10 regs, fp32, CSR
// order. v14 was still latency-bound (VALUBusy 19.6%): the per-iteration
// srcs->x dependent chain serialized ~500 cy per 2 edges. v15: unroll x4 +
// 1-stage srcs SOFTWARE PIPELINE — current window's srcs already in regs, so
// the 8 x-gathers issue immediately; next window's 4 srcs load in parallel
// with this window's recs/FMAs. ~24 loads in flight (was ~11).
// ---------------------------------------------------------------------------
__global__ __launch_bounds__(320)
void aggregate(const float* __restrict__ xin, const int* __restrict__ srcs,
               const float4* __restrict__ recs, const int* __restrict__ offs,
               unsigned short* __restrict__ Agg) {
    const int tid = threadIdx.x;
    const int ln  = tid / 80;            // local node 0..3
    const int cq  = tid - ln * 80;
    const int n   = blockIdx.x * 4 + ln; // NN = 2500*4 exactly
    const int q   = cq % 5;
    // transport partner: q=1<->2, q=3<->4; q=0 self
    const int qp   = (q == 0) ? 0 : ((q & 1) ? q + 1 : q - 1);
    const int pofs = cq - q + qp;
    const bool is0 = (q == 0);
    const bool hi  = (q >= 3);           // order-2 pair
    const float sgn = (q == 1 || q == 3) ? -1.0f : 1.0f;

    const int beg = offs[n], end = offs[n + 1];

    float acc[10];
    #pragma unroll
    for (int f = 0; f < 10; ++f) acc[f] = 0.0f;

#define EDGE_FMA(r0, r1, r2, xa, xb)                                          \
    do {                                                                      \
        const float c1 = (r2).z, s1 = (r2).w;                                 \
        const float c2 = c1 * c1 - s1 * s1;                                   \
        const float s2 = 2.0f * c1 * s1;                                      \
        const float Ac = is0 ? 1.0f : (hi ? c2 : c1);                         \
        const float Bc = is0 ? 0.0f : sgn * (hi ? s2 : s1);                   \
        const float xt = Ac * (xa) + Bc * (xb);                               \
        acc[0] += xt * (r0).x;  acc[1] += xt * (r0).y;                        \
        acc[2] += xt * (r0).z;  acc[3] += xt * (r0).w;                        \
        acc[4] += xt * (r1).x;  acc[5] += xt * (r1).y;                        \
        acc[6] += xt * (r1).z;  acc[7] += xt * (r1).w;                        \
        acc[8] += xt * (r2).x;  acc[9] += xt * (r2).y;                        \
    } while (0)

    if (beg < end) {
        int cs[4], ns[4];
        int idx = beg;
        #pragma unroll
        for (int j = 0; j < 4; ++j) {
            int t = idx + j;
            cs[j] = srcs[t < end ? t : end - 1];   // clamped prologue
        }
        for (; idx + 4 <= end; idx += 4) {
            // x gathers: addresses ready NOW (cs loaded last iteration)
            const float* xr0 = xin + (size_t)cs[0] * CQ;
            const float* xr1 = xin + (size_t)cs[1] * CQ;
            const float* xr2 = xin + (size_t)cs[2] * CQ;
            const float* xr3 = xin + (size_t)cs[3] * CQ;
            const float xa0 = xr0[cq], xb0 = xr0[pofs];
            const float xa1 = xr1[cq], xb1 = xr1[pofs];
            const float xa2 = xr2[cq], xb2 = xr2[pofs];
            const float xa3 = xr3[cq], xb3 = xr3[pofs];
            const float4* rp = recs + (size_t)idx * 3;
            const float4 r00 = rp[0],  r01 = rp[1],  r02 = rp[2];
            const float4 r10 = rp[3],  r11 = rp[4],  r12 = rp[5];
            const float4 r20 = rp[6],  r21 = rp[7],  r22 = rp[8];
            const float4 r30 = rp[9],  r31 = rp[10], r32 = rp[11];
            // prefetch next window's srcs (overlaps FMAs below)
            #pragma unroll
            for (int j = 0; j < 4; ++j) {
                int t = idx + 4 + j;
                ns[j] = srcs[t < end ? t : end - 1];
            }
            EDGE_FMA(r00, r01, r02, xa0, xb0);
            EDGE_FMA(r10, r11, r12, xa1, xb1);
            EDGE_FMA(r20, r21, r22, xa2, xb2);
            EDGE_FMA(r30, r31, r32, xa3, xb3);
            #pragma unroll
            for (int j = 0; j < 4; ++j) cs[j] = ns[j];
        }
        // tail (0..3 edges); cs[j] = srcs[idx+j] exactly for j < rem
        const int rem = end - idx;
        #pragma unroll
        for (int j = 0; j < 3; ++j) {
            if (j < rem) {
                const float* xr = xin + (size_t)cs[j] * CQ;
                const float xa = xr[cq], xb = xr[pofs];
                const float4* rp = recs + (size_t)(idx + j) * 3;
                const float4 r0 = rp[0], r1 = rp[1], r2 = rp[2];
                EDGE_FMA(r0, r1, r2, xa, xb);
            }
        }
    }
#undef EDGE_FMA

    unsigned* arw = (unsigned*)(Agg + (size_t)n * KTOT2 + cq * 10);  // 4B-aligned
    arw[0] = pack2h(acc[0], acc[1]);
    arw[1] = pack2h(acc[2], acc[3]);
    arw[2] = pack2h(acc[4], acc[5]);
    arw[3] = pack2h(acc[6], acc[7]);
    arw[4] = pack2h(acc[8], acc[9]);
    // self-interaction A part + zero pad
    Agg[(size_t)n * KTOT2 + 800 + cq] = f2h_u(xin[(size_t)n * CQ + cq]);
    if (cq < 16) Agg[(size_t)n * KTOT2 + 880 + cq] = 0;
}

// ---------------------------------------------------------------------------
// Node GEMM + fused nonlin (v15): y[16 x 80] = A'[16 x 896] @ B'[896 x 80]
// + bias (+ residual), then the 7-sample Fourier nonlinearity, written
// directly to the layer output. y never touches global memory.
// 5 waves, wave nt W-stationary in 112 VGPRs. A_s LDS reused as y_s (fp32)
// for the accumulator->epilogue transpose.
// ---------------------------------------------------------------------------
__global__ __launch_bounds__(320)
void node_gemm_nonlin(const unsigned short* __restrict__ Agg,
                      const unsigned short* __restrict__ Wt,
                      const float* __restrict__ b,
                      const float* __restrict__ res,   // residual (x) or nullptr
                      float* __restrict__ outp) {
    __shared__ __align__(16) unsigned char smem[16 * APAD * 2];  // 29,952 B
    unsigned short* A_s = (unsigned short*)smem;
    float* y_s = (float*)smem;                    // reused after barrier (5,120 B)

    const int tid = threadIdx.x;
    const int nt = tid >> 6, lane = tid & 63;
    const int lrow = lane & 15, quad = lane >> 4;
    const int n0 = blockIdx.x * 16;              // NN = 625*16 exactly

    const f16x8* __restrict__ wf = (const f16x8*)Wt;
    f16x8 breg[KS];
    #pragma unroll
    for (int ks = 0; ks < KS; ++ks)
        breg[ks] = wf[(ks * 5 + nt) * 64 + lane];

    // stage A: 16 rows x 1792 B = 1792 x 16B chunks over 320 threads
    {
        const uint4* srcp = (const uint4*)(Agg + (size_t)n0 * KTOT2);
        #pragma unroll
        for (int i = 0; i < 6; ++i) {
            int li = tid + 320 * i;              // 0..1919, use 0..1791
            if (li < 1792) {
                int row = li / 112, c16 = li % 112;
                *(uint4*)(&A_s[row * APAD + c16 * 8]) = srcp[row * 112 + c16];
            }
        }
    }
    __syncthreads();

    f32x4 acc = (f32x4){0.f, 0.f, 0.f, 0.f};
    #pragma unroll
    for (int ks = 0; ks < KS; ++ks) {
        f16x8 a = *(const f16x8*)(&A_s[lrow * APAD + 32 * ks + 8 * quad]);
        acc = __builtin_amdgcn_mfma_f32_16x16x32_f16(a, breg[ks], acc, 0, 0, 0);
    }
    __syncthreads();   // all A_s reads done; safe to overwrite as y_s

    const int op = 16 * nt + lrow;
    const float bias = (op % 5 == 0) ? b[op / 5] : 0.0f;
    #pragma unroll
    for (int r = 0; r < 4; ++r)
        y_s[(quad * 4 + r) * OP + op] = acc[r] + bias;
    __syncthreads();

    // epilogue: 256 threads, one (node, channel) each; nonlin + optional res
    if (tid < 256) {
        const int nl = tid >> 4;                 // node 0..15
        const int c  = tid & 15;                 // channel
        const float* vp = &y_s[nl * OP + c * 5];
        float a0 = vp[0], a1 = vp[1], a2 = vp[2], a3 = vp[3], a4 = vp[4];
        if (res != nullptr) {
            const float* rp = res + (size_t)(n0 + nl) * CQ + c * 5;
            a0 += rp[0]; a1 += rp[1]; a2 += rp[2]; a3 += rp[3]; a4 += rp[4];
        }
        float o0 = 0.f, o1 = 0.f, o2 = 0.f, o3 = 0.f, o4 = 0.f;
        #pragma unroll
        for (int k = 0; k < 7; ++k) {
            float th = (float)(2.0 * M_PI / 7.0) * (float)k;
            float c1k = cosf(th), s1k = sinf(th);
            float c2k = cosf(2.0f * th), s2k = sinf(2.0f * th);
            float s = a0 + a1 * c1k + a2 * s1k + a3 * c2k + a4 * s2k;
            s = fmaxf(s, 0.0f);
            o0 += s;
            o1 += s * c1k; o2 += s * s1k;
            o3 += s * c2k; o4 += s * s2k;
        }
        const float i7 = 1.0f / 7.0f, t7 = 2.0f / 7.0f;
        float* po = outp + (size_t)(n0 + nl) * OP + c * 5;
        po[0] = o0 * i7;
        po[1] = o1 * t7; po[2] = o2 * t7;
        po[3] = o3 * t7; po[4] = o4 * t7;
    }
}

// ---------------------------------------------------------------------------
extern "C" void kernel_launch(void* const* d_in, const int* in_sizes, int n_in,
                              void* d_out, int out_size, void* d_ws, size_t ws_size,
                              hipStream_t stream) {
    const float* x    = (const float*)d_in[0];
    const int*   ei   = (const int*)d_in[1];      // int inputs arrive as int32
    const float* pre  = (const float*)d_in[2];
    const float* phi  = (const float*)d_in[3];
    const float* W1   = (const float*)d_in[4];
    const float* b1   = (const float*)d_in[5];
    const float* Ws1  = (const float*)d_in[6];
    const float* W2   = (const float*)d_in[7];
    const float* b2   = (const float*)d_in[8];
    const float* Ws2  = (const float*)d_in[9];
    float* out = (float*)d_out;

    // Workspace layout (~30 MB)
    unsigned short* Wt1 = (unsigned short*)d_ws;            // 143.4 KB
    unsigned short* Wt2 = Wt1 + WTN;                        // 143.4 KB
    float* h  = (float*)(Wt2 + WTN);                        // 3.2 MB
    unsigned short* Agg = (unsigned short*)(h + (size_t)NN * OP);  // 17.92 MB
    float4* recs = (float4*)(Agg + (size_t)NN * KTOT2);     // 7.68 MB (16B aligned)
    int* srcs   = (int*)(recs + (size_t)NE * 3);            // 640 KB
    int* cnt    = srcs + NE;                                // 40 KB
    int* offs   = cnt + NN;                                 // 40 KB
    int* cursor = offs + NN + 1;                            // 40 KB

    // prep: hist + W/Ws reorder; scan; place+gather (stream-ordered records)
    hipMemsetAsync(cnt, 0, NN * sizeof(int), stream);
    prep_all<<<(NE + 255) / 256, 256, 0, stream>>>(ei, W1, Ws1, W2, Ws2, cnt, Wt1, Wt2);
    csr_scan<<<1, 1024, 0, stream>>>(cnt, offs, cursor);
    csr_place_gather<<<(NE + 255) / 256, 256, 0, stream>>>(ei, phi, pre, cursor, srcs, recs);

    // Layer 1
    aggregate<<<NN / 4, 320, 0, stream>>>(x, srcs, recs, offs, Agg);
    node_gemm_nonlin<<<NN / 16, 320, 0, stream>>>(Agg, Wt1, b1, nullptr, h);

    // Layer 2
    aggregate<<<NN / 4, 320, 0, stream>>>(h, srcs, recs, offs, Agg);
    node_gemm_nonlin<<<NN / 16, 320, 0, stream>>>(Agg, Wt2, b2, x, out);
}